// Round 1
// baseline (383.925 us; speedup 1.0000x reference)
//
#include <hip/hip_runtime.h>
#include <math.h>

// VQVAE loss: total = huber_mean(x_hat - x) + 0.1 * mean_b(softDTW(x, x_hat)) + commit
// B=64, L=512, C=16, gamma=0.1, INF=1e10.
//
// Design:
//  - huber_kernel: 4MB streamed, per-block partials (no atomics).
//  - gemm_diag_kernel: per 64x64 tile, computes P(i,j) = x_i . y_j - 0.5*||y_j||^2,
//    stores packed by anti-diagonal: Dp[b][off(k) + i - i0(k)] (262144 cells/batch, no holes).
//  - dtw_kernel: 1 block/batch, 512 threads (thread = row i), 1023 barrier-steps.
//    Per step: coalesced prefetched read of P, 2 LDS reads (a,b), own prev in register (c),
//    1 LDS write. softmin via exp2/log2: res = m - (g*ln2)*log2(sum exp2((m-v)*log2e/g)).
//  - fallback fused kernel if ws too small (on-the-fly dot).

#define INFV 1.0e10f
static constexpr float kC1 = 14.4269504088896f;    // log2(e)/gamma  (gamma=0.1)
static constexpr float kC2 = 0.0693147180559945f;  // gamma*ln(2)

// cells before anti-diagonal k (per batch), L=512; total = 262144
__device__ __forceinline__ int diag_off(int k) {
  if (k <= 512) return (k * (k + 1)) >> 1;
  int u = k - 512;
  return 131328 + 511 * u - ((u * (u - 1)) >> 1);
}
__device__ __forceinline__ int diag_i0(int k) { return k < 512 ? 0 : k - 511; }

// ---------------- Huber ----------------
__device__ __forceinline__ float huber1(float d) {
  float ad = fabsf(d);
  return ad <= 1.0f ? 0.5f * d * d : ad - 0.5f;
}

__global__ __launch_bounds__(256) void huber_kernel(const float* __restrict__ x,
                                                    const float* __restrict__ xh,
                                                    float* __restrict__ part) {
  int t = threadIdx.x;
  int gid = blockIdx.x * 256 + t;
  float s = 0.f;
  // N = 64*512*16 = 524288 floats = 131072 float4; grid 256*256 threads -> 2 iters
  for (int i = gid; i < 131072; i += 65536) {
    float4 a = ((const float4*)x)[i];
    float4 b = ((const float4*)xh)[i];
    s += huber1(b.x - a.x) + huber1(b.y - a.y) + huber1(b.z - a.z) + huber1(b.w - a.w);
  }
  for (int o = 32; o > 0; o >>= 1) s += __shfl_down(s, o, 64);
  __shared__ float ws4[4];
  if ((t & 63) == 0) ws4[t >> 6] = s;
  __syncthreads();
  if (t == 0) part[blockIdx.x] = ws4[0] + ws4[1] + ws4[2] + ws4[3];
}

// ---------------- GEMM -> packed-diagonal P ----------------
__global__ __launch_bounds__(256) void gemm_diag_kernel(const float* __restrict__ x,
                                                        const float* __restrict__ xh,
                                                        float* __restrict__ Dp) {
  const int b = blockIdx.z;
  const int ti = blockIdx.x;  // x-row tile
  const int tj = blockIdx.y;  // xh-row tile
  const int t = threadIdx.x;
  __shared__ float sm[64 * 67];  // aliased: xsT[16][68], ysT[16][68]; later tile[64][67]
  float* xsT = sm;
  float* ysT = sm + 16 * 68;
  const float* xb = x + ((size_t)b * 8192) + ti * 1024;
  const float* yb = xh + ((size_t)b * 8192) + tj * 1024;
  {
    float4 xv = ((const float4*)xb)[t];
    float4 yv = ((const float4*)yb)[t];
    int r = t >> 2, c0 = (t & 3) << 2;
    xsT[(c0 + 0) * 68 + r] = xv.x;
    xsT[(c0 + 1) * 68 + r] = xv.y;
    xsT[(c0 + 2) * 68 + r] = xv.z;
    xsT[(c0 + 3) * 68 + r] = xv.w;
    ysT[(c0 + 0) * 68 + r] = yv.x;
    ysT[(c0 + 1) * 68 + r] = yv.y;
    ysT[(c0 + 2) * 68 + r] = yv.z;
    ysT[(c0 + 3) * 68 + r] = yv.w;
  }
  __syncthreads();
  const int tm = t & 15, tn = t >> 4;
  float acc[4][4] = {};
  float y2a[4] = {};
#pragma unroll
  for (int c = 0; c < 16; ++c) {
    float4 xv = *(const float4*)&xsT[c * 68 + tm * 4];
    float4 yv = *(const float4*)&ysT[c * 68 + tn * 4];
    float xr[4] = {xv.x, xv.y, xv.z, xv.w};
    float yr[4] = {yv.x, yv.y, yv.z, yv.w};
#pragma unroll
    for (int n = 0; n < 4; ++n) {
      y2a[n] = fmaf(yr[n], yr[n], y2a[n]);
#pragma unroll
      for (int m = 0; m < 4; ++m) acc[m][n] = fmaf(xr[m], yr[n], acc[m][n]);
    }
  }
  __syncthreads();  // done reading xsT/ysT; reuse sm as tile[64][67]
#pragma unroll
  for (int m = 0; m < 4; ++m)
#pragma unroll
    for (int n = 0; n < 4; ++n)
      sm[(tm * 4 + m) * 67 + (tn * 4 + n)] = acc[m][n] - 0.5f * y2a[n];
  __syncthreads();
  const int lane = t & 63, wv = t >> 6;
  float* outb = Dp + (size_t)b * 262144;
  const int kbase = ti * 64 + tj * 64;
  for (int s = wv; s < 127; s += 4) {
    int ilo = s > 63 ? s - 63 : 0;
    int ihi = s < 63 ? s : 63;
    if (lane >= ilo && lane <= ihi) {
      float v = sm[lane * 67 + (s - lane)];
      int k = kbase + s;
      outb[diag_off(k) - diag_i0(k) + (ti * 64 + lane)] = v;
    }
  }
}

// ---------------- DTW (precomputed P path) ----------------
// buffers rotate; c-operand (own prev) lives in register vprev.
#define DTW_STEP(PD, W, R1, R2)                                             \
  do {                                                                      \
    int j = k - tid;                                                        \
    bool valid = (j >= 0) && (j < 512);                                     \
    float av = R2[tid];                                                     \
    float bv = R1[tid];                                                     \
    float dotv = PD;                                                        \
    if (k + 3 <= 1022) PD = Db[diag_off(k + 3) - diag_i0(k + 3) + tid];     \
    float mv = fminf(fminf(av, bv), vprev);                                 \
    float ssum = exp2f((mv - av) * kC1) + exp2f((mv - bv) * kC1) +          \
                 exp2f((mv - vprev) * kC1);                                 \
    float sm3 = fmaf(-kC2, log2f(ssum), mv);                                \
    float dd = fmaf(-2.0f, dotv, x2);                                       \
    float val = valid ? (dd + sm3) : INFV;                                  \
    W[tid + 1] = val;                                                       \
    vprev = val;                                                            \
    __syncthreads();                                                        \
    ++k;                                                                    \
  } while (0)

__global__ __launch_bounds__(512) void dtw_kernel(const float* __restrict__ x,
                                                  const float* __restrict__ Dp,
                                                  float* __restrict__ outv) {
  const int b = blockIdx.x;
  const int tid = threadIdx.x;
  __shared__ float rA[516], rB[516], rC[516];
  const float* xr = x + (size_t)b * 8192 + tid * 16;
  float x2 = 0.f;
#pragma unroll
  for (int c = 0; c < 16; c += 4) {
    float4 v = *(const float4*)(xr + c);
    x2 += v.x * v.x + v.y * v.y + v.z * v.z + v.w * v.w;
  }
  rA[tid] = INFV;
  rB[tid] = INFV;
  rC[tid] = INFV;
  if (tid == 0) { rA[512] = INFV; rB[512] = INFV; rC[512] = INFV; }
  const float* Db = Dp + (size_t)b * 262144;
  float p0 = Db[tid];      // k=0
  float p1 = Db[1 + tid];  // k=1
  float p2 = Db[3 + tid];  // k=2
  // peel k=0: only cell (0,0); softmin(0,INF,INF)=0 exactly -> val = d(0,0)
  float d00 = fmaf(-2.0f, p0, x2);
  float vprev = (tid == 0) ? d00 : INFV;
  if (tid == 0) rC[1] = d00;
  p0 = Db[diag_off(3) + tid];  // reload slot for k=3 (i0=0)
  int k = 1;
  __syncthreads();
#pragma unroll 1
  for (int it = 0; it < 340; ++it) {
    DTW_STEP(p1, rA, rC, rB);  // k % 3 == 1
    DTW_STEP(p2, rB, rA, rC);  // k % 3 == 2
    DTW_STEP(p0, rC, rB, rA);  // k % 3 == 0
  }
  DTW_STEP(p1, rA, rC, rB);  // k = 1021
  DTW_STEP(p2, rB, rA, rC);  // k = 1022 -> cell (511,511) in vprev of tid 511
  if (tid == 511) outv[b] = vprev;
}

// ---------------- DTW fallback (fused dot, no workspace matrix) ----------------
__device__ __forceinline__ float dot16(const float4& a, const float4& b2,
                                       const float4& c, const float4& d,
                                       const float4* yp) {
  float4 q0 = yp[0], q1 = yp[1], q2 = yp[2], q3 = yp[3];
  float s = a.x * q0.x;
  s = fmaf(a.y, q0.y, s); s = fmaf(a.z, q0.z, s); s = fmaf(a.w, q0.w, s);
  s = fmaf(b2.x, q1.x, s); s = fmaf(b2.y, q1.y, s); s = fmaf(b2.z, q1.z, s); s = fmaf(b2.w, q1.w, s);
  s = fmaf(c.x, q2.x, s); s = fmaf(c.y, q2.y, s); s = fmaf(c.z, q2.z, s); s = fmaf(c.w, q2.w, s);
  s = fmaf(d.x, q3.x, s); s = fmaf(d.y, q3.y, s); s = fmaf(d.z, q3.z, s); s = fmaf(d.w, q3.w, s);
  return s;
}

#define DTW_FSTEP(W, R1, R2)                                                \
  do {                                                                      \
    int j = k - tid;                                                        \
    bool valid = (j >= 0) && (j < 512);                                     \
    int jc = valid ? j : 0;                                                 \
    float av = R2[tid];                                                     \
    float bv = R1[tid];                                                     \
    float dotv = dot16(xa, xb4, xc4, xd4, (const float4*)&ysl[jc * 20]);    \
    float mv = fminf(fminf(av, bv), vprev);                                 \
    float ssum = exp2f((mv - av) * kC1) + exp2f((mv - bv) * kC1) +          \
                 exp2f((mv - vprev) * kC1);                                 \
    float sm3 = fmaf(-kC2, log2f(ssum), mv);                                \
    float dd = fmaf(-2.0f, dotv, x2 + y2s[jc]);                             \
    float val = valid ? (dd + sm3) : INFV;                                  \
    W[tid + 1] = val;                                                       \
    vprev = val;                                                            \
    __syncthreads();                                                        \
    ++k;                                                                    \
  } while (0)

__global__ __launch_bounds__(512) void dtw_fused_kernel(const float* __restrict__ x,
                                                        const float* __restrict__ xh,
                                                        float* __restrict__ outv) {
  const int b = blockIdx.x;
  const int tid = threadIdx.x;
  __shared__ float ysl[512 * 20];  // row stride 20 floats (80B, float4-aligned)
  __shared__ float y2s[512];
  __shared__ float rA[516], rB[516], rC[516];
  const float* xr = x + (size_t)b * 8192 + tid * 16;
  const float* yr = xh + (size_t)b * 8192 + tid * 16;
  float4 xa = *(const float4*)(xr + 0);
  float4 xb4 = *(const float4*)(xr + 4);
  float4 xc4 = *(const float4*)(xr + 8);
  float4 xd4 = *(const float4*)(xr + 12);
  float x2 = xa.x * xa.x + xa.y * xa.y + xa.z * xa.z + xa.w * xa.w +
             xb4.x * xb4.x + xb4.y * xb4.y + xb4.z * xb4.z + xb4.w * xb4.w +
             xc4.x * xc4.x + xc4.y * xc4.y + xc4.z * xc4.z + xc4.w * xc4.w +
             xd4.x * xd4.x + xd4.y * xd4.y + xd4.z * xd4.z + xd4.w * xd4.w;
  {
    float4 q0 = *(const float4*)(yr + 0);
    float4 q1 = *(const float4*)(yr + 4);
    float4 q2 = *(const float4*)(yr + 8);
    float4 q3 = *(const float4*)(yr + 12);
    *(float4*)&ysl[tid * 20 + 0] = q0;
    *(float4*)&ysl[tid * 20 + 4] = q1;
    *(float4*)&ysl[tid * 20 + 8] = q2;
    *(float4*)&ysl[tid * 20 + 12] = q3;
    y2s[tid] = q0.x * q0.x + q0.y * q0.y + q0.z * q0.z + q0.w * q0.w +
               q1.x * q1.x + q1.y * q1.y + q1.z * q1.z + q1.w * q1.w +
               q2.x * q2.x + q2.y * q2.y + q2.z * q2.z + q2.w * q2.w +
               q3.x * q3.x + q3.y * q3.y + q3.z * q3.z + q3.w * q3.w;
  }
  rA[tid] = INFV;
  rB[tid] = INFV;
  rC[tid] = INFV;
  if (tid == 0) { rA[512] = INFV; rB[512] = INFV; rC[512] = INFV; }
  __syncthreads();
  // peel k=0
  float dot00 = dot16(xa, xb4, xc4, xd4, (const float4*)&ysl[0]);
  float d00 = fmaf(-2.0f, dot00, x2 + y2s[0]);
  float vprev = (tid == 0) ? d00 : INFV;
  if (tid == 0) rC[1] = d00;
  int k = 1;
  __syncthreads();
#pragma unroll 1
  for (int it = 0; it < 340; ++it) {
    DTW_FSTEP(rA, rC, rB);
    DTW_FSTEP(rB, rA, rC);
    DTW_FSTEP(rC, rB, rA);
  }
  DTW_FSTEP(rA, rC, rB);
  DTW_FSTEP(rB, rA, rC);
  if (tid == 511) outv[b] = vprev;
}

// ---------------- finalize ----------------
__global__ __launch_bounds__(256) void finalize_kernel(const float* __restrict__ part,
                                                       const float* __restrict__ dtwv,
                                                       const float* __restrict__ commit,
                                                       float* __restrict__ out) {
  int t = threadIdx.x;
  float h = part[t];                      // 256 partials
  float dv = (t < 64) ? dtwv[t] : 0.f;    // 64 per-batch dtw values (wave 0)
  for (int o = 32; o > 0; o >>= 1) {
    h += __shfl_down(h, o, 64);
    dv += __shfl_down(dv, o, 64);
  }
  __shared__ float sh[4], sd[4];
  if ((t & 63) == 0) { sh[t >> 6] = h; sd[t >> 6] = dv; }
  __syncthreads();
  if (t == 0) {
    float hs = sh[0] + sh[1] + sh[2] + sh[3];
    float ds = sd[0] + sd[1] + sd[2] + sd[3];
    float hm = hs * (1.0f / 524288.0f);          // mean over B*L*C
    float smv = ds * (0.1f / 64.0f);             // alpha * mean over B
    float cm = commit[0];
    out[0] = hm + smv + cm;
    out[1] = hm;
    out[2] = smv;
    out[3] = cm;
  }
}

extern "C" void kernel_launch(void* const* d_in, const int* in_sizes, int n_in,
                              void* d_out, int out_size, void* d_ws, size_t ws_size,
                              hipStream_t stream) {
  (void)in_sizes; (void)n_in; (void)out_size;
  const float* x = (const float*)d_in[0];
  const float* xh = (const float*)d_in[1];
  const float* commit = (const float*)d_in[2];
  float* out = (float*)d_out;
  float* ws = (float*)d_ws;
  float* part = ws;         // 256 floats
  float* dtwv = ws + 256;   // 64 floats
  float* Dp = ws + 512;     // 64 * 262144 floats (packed-diagonal P)
  const size_t need = 2048 + (size_t)64 * 262144 * 4;

  huber_kernel<<<256, 256, 0, stream>>>(x, xh, part);
  if (ws_size >= need) {
    gemm_diag_kernel<<<dim3(8, 8, 64), 256, 0, stream>>>(x, xh, Dp);
    dtw_kernel<<<64, 512, 0, stream>>>(x, Dp, dtwv);
  } else {
    dtw_fused_kernel<<<64, 512, 0, stream>>>(x, xh, dtwv);
  }
  finalize_kernel<<<1, 256, 0, stream>>>(part, dtwv, commit, out);
}

// Round 2
// 353.012 us; speedup vs baseline: 1.0876x; 1.0876x over previous
//
#include <hip/hip_runtime.h>
#include <math.h>

// VQVAE loss: total = huber_mean(x_hat - x) + 0.1 * mean_b(softDTW(x, x_hat)) + commit
// B=64, L=512, C=16, gamma=0.1, INF=1e10.
//
// Round 2: DTW rewritten as intra-block wave pipeline (no per-step barrier).
//  - 64 blocks (1/batch) x 512 threads; wave w owns rows [64w, 64w+64), lane = row.
//  - neighbor (i-1) values via __shfl_up; wave boundary row via LDS ring + flag,
//    published every 10 steps (waves of a block are co-resident -> spin is safe).
//  - each wave runs only its 575 live diagonals (k in [64w, 64w+574]).
//  - P(i,j) = x_i.y_j - 0.5*||y_j||^2 precomputed diagonal-packed (gemm_diag_kernel),
//    prefetched 10 deep per lane.

#define INFV 1.0e10f
static constexpr float kC1 = 14.4269504088896f;    // log2(e)/gamma  (gamma=0.1)
static constexpr float kC2 = 0.0693147180559945f;  // gamma*ln(2)

// cells before anti-diagonal k (per batch), L=512; total = 262144
__device__ __forceinline__ int diag_off(int k) {
  if (k <= 512) return (k * (k + 1)) >> 1;
  int u = k - 512;
  return 131328 + 511 * u - ((u * (u - 1)) >> 1);
}
__device__ __forceinline__ int diag_i0(int k) { return k < 512 ? 0 : k - 511; }

// ---------------- Huber ----------------
__device__ __forceinline__ float huber1(float d) {
  float ad = fabsf(d);
  return ad <= 1.0f ? 0.5f * d * d : ad - 0.5f;
}

__global__ __launch_bounds__(256) void huber_kernel(const float* __restrict__ x,
                                                    const float* __restrict__ xh,
                                                    float* __restrict__ part) {
  int t = threadIdx.x;
  int gid = blockIdx.x * 256 + t;
  float s = 0.f;
  for (int i = gid; i < 131072; i += 65536) {
    float4 a = ((const float4*)x)[i];
    float4 b = ((const float4*)xh)[i];
    s += huber1(b.x - a.x) + huber1(b.y - a.y) + huber1(b.z - a.z) + huber1(b.w - a.w);
  }
  for (int o = 32; o > 0; o >>= 1) s += __shfl_down(s, o, 64);
  __shared__ float ws4[4];
  if ((t & 63) == 0) ws4[t >> 6] = s;
  __syncthreads();
  if (t == 0) part[blockIdx.x] = ws4[0] + ws4[1] + ws4[2] + ws4[3];
}

// ---------------- GEMM -> packed-diagonal P ----------------
__global__ __launch_bounds__(256) void gemm_diag_kernel(const float* __restrict__ x,
                                                        const float* __restrict__ xh,
                                                        float* __restrict__ Dp) {
  const int b = blockIdx.z;
  const int ti = blockIdx.x;
  const int tj = blockIdx.y;
  const int t = threadIdx.x;
  __shared__ float sm[64 * 67];
  float* xsT = sm;
  float* ysT = sm + 16 * 68;
  const float* xb = x + ((size_t)b * 8192) + ti * 1024;
  const float* yb = xh + ((size_t)b * 8192) + tj * 1024;
  {
    float4 xv = ((const float4*)xb)[t];
    float4 yv = ((const float4*)yb)[t];
    int r = t >> 2, c0 = (t & 3) << 2;
    xsT[(c0 + 0) * 68 + r] = xv.x;
    xsT[(c0 + 1) * 68 + r] = xv.y;
    xsT[(c0 + 2) * 68 + r] = xv.z;
    xsT[(c0 + 3) * 68 + r] = xv.w;
    ysT[(c0 + 0) * 68 + r] = yv.x;
    ysT[(c0 + 1) * 68 + r] = yv.y;
    ysT[(c0 + 2) * 68 + r] = yv.z;
    ysT[(c0 + 3) * 68 + r] = yv.w;
  }
  __syncthreads();
  const int tm = t & 15, tn = t >> 4;
  float acc[4][4] = {};
  float y2a[4] = {};
#pragma unroll
  for (int c = 0; c < 16; ++c) {
    float4 xv = *(const float4*)&xsT[c * 68 + tm * 4];
    float4 yv = *(const float4*)&ysT[c * 68 + tn * 4];
    float xr[4] = {xv.x, xv.y, xv.z, xv.w};
    float yr[4] = {yv.x, yv.y, yv.z, yv.w};
#pragma unroll
    for (int n = 0; n < 4; ++n) {
      y2a[n] = fmaf(yr[n], yr[n], y2a[n]);
#pragma unroll
      for (int m = 0; m < 4; ++m) acc[m][n] = fmaf(xr[m], yr[n], acc[m][n]);
    }
  }
  __syncthreads();
#pragma unroll
  for (int m = 0; m < 4; ++m)
#pragma unroll
    for (int n = 0; n < 4; ++n)
      sm[(tm * 4 + m) * 67 + (tn * 4 + n)] = acc[m][n] - 0.5f * y2a[n];
  __syncthreads();
  const int lane = t & 63, wv = t >> 6;
  float* outb = Dp + (size_t)b * 262144;
  const int kbase = ti * 64 + tj * 64;
  for (int s = wv; s < 127; s += 4) {
    int ilo = s > 63 ? s - 63 : 0;
    int ihi = s < 63 ? s : 63;
    if (lane >= ilo && lane <= ihi) {
      float v = sm[lane * 67 + (s - lane)];
      int k = kbase + s;
      outb[diag_off(k) - diag_i0(k) + (ti * 64 + lane)] = v;
    }
  }
}

// ---------------- DTW: wave-pipelined, no per-step barrier ----------------
// Per step: softmin(a,b,c) with the exact identity exp2((m-min)*C1)==1:
//   ssum = 1 + exp2((m-med)*C1) + exp2((m-max)*C1)   (med3/max3)
#define PSTEP(PN)                                                           \
  do {                                                                      \
    float bval = __shfl_up(vprev, 1);                                       \
    float rv = ringPrev[min(kk + 63, 574)];                                 \
    if (lane == 0) bval = (w == 0) ? INFV : rv;                             \
    float mv = fminf(fminf(aval, bval), vprev);                             \
    float md = __builtin_amdgcn_fmed3f(aval, bval, vprev);                  \
    float mx = fmaxf(fmaxf(aval, bval), vprev);                             \
    float ssum = 1.0f + exp2f((mv - md) * kC1) + exp2f((mv - mx) * kC1);    \
    float sm3 = fmaf(-kC2, log2f(ssum), mv);                                \
    float dotv = PN;                                                        \
    {                                                                       \
      int kc = k0 + min(kk + 10, 574);                                      \
      PN = DbL[diag_off(kc) - diag_i0(kc)];                                 \
    }                                                                       \
    float dd = fmaf(-2.0f, dotv, x2);                                       \
    float val = ((unsigned)(kk - lane) <= 511u) ? (dd + sm3) : INFV;        \
    if (lane == 63) ringOwn[kk] = val;                                      \
    aval = bval;                                                            \
    vprev = val;                                                            \
    ++kk;                                                                   \
  } while (0)

__global__ __launch_bounds__(512) void dtw_pipe_kernel(const float* __restrict__ x,
                                                       const float* __restrict__ Dp,
                                                       float* __restrict__ outv) {
  const int b = blockIdx.x;
  const int tid = threadIdx.x;
  const int w = tid >> 6;
  const int lane = tid & 63;
  __shared__ float ring[8][576];
  __shared__ int flags[8];
  if (tid < 8) flags[tid] = 0;
  __syncthreads();
  volatile int* vflags = flags;

  const int i = (w << 6) | lane;  // row
  const float* xr = x + (size_t)b * 8192 + i * 16;
  float x2 = 0.f;
#pragma unroll
  for (int c = 0; c < 16; c += 4) {
    float4 v = *(const float4*)(xr + c);
    x2 += v.x * v.x + v.y * v.y + v.z * v.z + v.w * v.w;
  }
  const float* DbL = Dp + (size_t)b * 262144 + i;  // per-lane base
  const int k0 = w << 6;

  float p[10];
#pragma unroll
  for (int n = 0; n < 10; ++n) {
    int kg = k0 + n;
    p[n] = DbL[diag_off(kg) - diag_i0(kg)];
  }

  // virtual corner R(-1,-1)=0 feeds cell (0,0)'s a-operand
  float aval = (w == 0 && lane == 0) ? 0.0f : INFV;
  float vprev = INFV;
  float* ringOwn = ring[w];
  const float* ringPrev = ring[(w == 0) ? 7 : (w - 1)];

  int kk = 0;  // local step; global diag k = k0 + kk; 575 steps total
#pragma unroll 1
  for (int ss = 0; ss < 58; ++ss) {
    const int nsub = (ss == 57) ? 5 : 10;
    if (w != 0) {
      const int need = min(kk + nsub + 63, 575);
      while (vflags[w - 1] < need) {
      }
      __threadfence_block();  // order ring reads after flag observation
    }
    if (nsub == 10) {
      PSTEP(p[0]); PSTEP(p[1]); PSTEP(p[2]); PSTEP(p[3]); PSTEP(p[4]);
      PSTEP(p[5]); PSTEP(p[6]); PSTEP(p[7]); PSTEP(p[8]); PSTEP(p[9]);
    } else {
      PSTEP(p[0]); PSTEP(p[1]); PSTEP(p[2]); PSTEP(p[3]); PSTEP(p[4]);
    }
    __threadfence_block();  // ring writes visible before flag publish
    if (lane == 63) vflags[w] = kk;
  }
  if (tid == 511) outv[b] = vprev;  // wave 7 lane 63: cell (511,511)
}

// ---------------- DTW fallback (fused dot, no workspace matrix) ----------------
__device__ __forceinline__ float dot16(const float4& a, const float4& b2,
                                       const float4& c, const float4& d,
                                       const float4* yp) {
  float4 q0 = yp[0], q1 = yp[1], q2 = yp[2], q3 = yp[3];
  float s = a.x * q0.x;
  s = fmaf(a.y, q0.y, s); s = fmaf(a.z, q0.z, s); s = fmaf(a.w, q0.w, s);
  s = fmaf(b2.x, q1.x, s); s = fmaf(b2.y, q1.y, s); s = fmaf(b2.z, q1.z, s); s = fmaf(b2.w, q1.w, s);
  s = fmaf(c.x, q2.x, s); s = fmaf(c.y, q2.y, s); s = fmaf(c.w, q2.w, s); s = fmaf(c.z, q2.z, s);
  s = fmaf(d.x, q3.x, s); s = fmaf(d.y, q3.y, s); s = fmaf(d.z, q3.z, s); s = fmaf(d.w, q3.w, s);
  return s;
}

#define DTW_FSTEP(W, R1, R2)                                                \
  do {                                                                      \
    int j = k - tid;                                                        \
    bool valid = (j >= 0) && (j < 512);                                     \
    int jc = valid ? j : 0;                                                 \
    float av = R2[tid];                                                     \
    float bv = R1[tid];                                                     \
    float dotv = dot16(xa, xb4, xc4, xd4, (const float4*)&ysl[jc * 20]);    \
    float mv = fminf(fminf(av, bv), vprev);                                 \
    float ssum = exp2f((mv - av) * kC1) + exp2f((mv - bv) * kC1) +          \
                 exp2f((mv - vprev) * kC1);                                 \
    float sm3 = fmaf(-kC2, log2f(ssum), mv);                                \
    float dd = fmaf(-2.0f, dotv, x2 + y2s[jc]);                             \
    float val = valid ? (dd + sm3) : INFV;                                  \
    W[tid + 1] = val;                                                       \
    vprev = val;                                                            \
    __syncthreads();                                                        \
    ++k;                                                                    \
  } while (0)

__global__ __launch_bounds__(512) void dtw_fused_kernel(const float* __restrict__ x,
                                                        const float* __restrict__ xh,
                                                        float* __restrict__ outv) {
  const int b = blockIdx.x;
  const int tid = threadIdx.x;
  __shared__ float ysl[512 * 20];
  __shared__ float y2s[512];
  __shared__ float rA[516], rB[516], rC[516];
  const float* xr = x + (size_t)b * 8192 + tid * 16;
  const float* yr = xh + (size_t)b * 8192 + tid * 16;
  float4 xa = *(const float4*)(xr + 0);
  float4 xb4 = *(const float4*)(xr + 4);
  float4 xc4 = *(const float4*)(xr + 8);
  float4 xd4 = *(const float4*)(xr + 12);
  float x2 = xa.x * xa.x + xa.y * xa.y + xa.z * xa.z + xa.w * xa.w +
             xb4.x * xb4.x + xb4.y * xb4.y + xb4.z * xb4.z + xb4.w * xb4.w +
             xc4.x * xc4.x + xc4.y * xc4.y + xc4.z * xc4.z + xc4.w * xc4.w +
             xd4.x * xd4.x + xd4.y * xd4.y + xd4.z * xd4.z + xd4.w * xd4.w;
  {
    float4 q0 = *(const float4*)(yr + 0);
    float4 q1 = *(const float4*)(yr + 4);
    float4 q2 = *(const float4*)(yr + 8);
    float4 q3 = *(const float4*)(yr + 12);
    *(float4*)&ysl[tid * 20 + 0] = q0;
    *(float4*)&ysl[tid * 20 + 4] = q1;
    *(float4*)&ysl[tid * 20 + 8] = q2;
    *(float4*)&ysl[tid * 20 + 12] = q3;
    y2s[tid] = q0.x * q0.x + q0.y * q0.y + q0.z * q0.z + q0.w * q0.w +
               q1.x * q1.x + q1.y * q1.y + q1.z * q1.z + q1.w * q1.w +
               q2.x * q2.x + q2.y * q2.y + q2.z * q2.z + q2.w * q2.w +
               q3.x * q3.x + q3.y * q3.y + q3.z * q3.z + q3.w * q3.w;
  }
  rA[tid] = INFV;
  rB[tid] = INFV;
  rC[tid] = INFV;
  if (tid == 0) { rA[512] = INFV; rB[512] = INFV; rC[512] = INFV; }
  __syncthreads();
  float dot00 = dot16(xa, xb4, xc4, xd4, (const float4*)&ysl[0]);
  float d00 = fmaf(-2.0f, dot00, x2 + y2s[0]);
  float vprev = (tid == 0) ? d00 : INFV;
  if (tid == 0) rC[1] = d00;
  int k = 1;
  __syncthreads();
#pragma unroll 1
  for (int it = 0; it < 340; ++it) {
    DTW_FSTEP(rA, rC, rB);
    DTW_FSTEP(rB, rA, rC);
    DTW_FSTEP(rC, rB, rA);
  }
  DTW_FSTEP(rA, rC, rB);
  DTW_FSTEP(rB, rA, rC);
  if (tid == 511) outv[b] = vprev;
}

// ---------------- finalize ----------------
__global__ __launch_bounds__(256) void finalize_kernel(const float* __restrict__ part,
                                                       const float* __restrict__ dtwv,
                                                       const float* __restrict__ commit,
                                                       float* __restrict__ out) {
  int t = threadIdx.x;
  float h = part[t];
  float dv = (t < 64) ? dtwv[t] : 0.f;
  for (int o = 32; o > 0; o >>= 1) {
    h += __shfl_down(h, o, 64);
    dv += __shfl_down(dv, o, 64);
  }
  __shared__ float sh[4], sd[4];
  if ((t & 63) == 0) { sh[t >> 6] = h; sd[t >> 6] = dv; }
  __syncthreads();
  if (t == 0) {
    float hs = sh[0] + sh[1] + sh[2] + sh[3];
    float ds = sd[0] + sd[1] + sd[2] + sd[3];
    float hm = hs * (1.0f / 524288.0f);
    float smv = ds * (0.1f / 64.0f);
    float cm = commit[0];
    out[0] = hm + smv + cm;
    out[1] = hm;
    out[2] = smv;
    out[3] = cm;
  }
}

extern "C" void kernel_launch(void* const* d_in, const int* in_sizes, int n_in,
                              void* d_out, int out_size, void* d_ws, size_t ws_size,
                              hipStream_t stream) {
  (void)in_sizes; (void)n_in; (void)out_size;
  const float* x = (const float*)d_in[0];
  const float* xh = (const float*)d_in[1];
  const float* commit = (const float*)d_in[2];
  float* out = (float*)d_out;
  float* ws = (float*)d_ws;
  float* part = ws;        // 256 floats
  float* dtwv = ws + 256;  // 64 floats
  float* Dp = ws + 512;    // 64 * 262144 floats
  const size_t need = 2048 + (size_t)64 * 262144 * 4;

  huber_kernel<<<256, 256, 0, stream>>>(x, xh, part);
  if (ws_size >= need) {
    gemm_diag_kernel<<<dim3(8, 8, 64), 256, 0, stream>>>(x, xh, Dp);
    dtw_pipe_kernel<<<64, 512, 0, stream>>>(x, Dp, dtwv);
  } else {
    dtw_fused_kernel<<<64, 512, 0, stream>>>(x, xh, dtwv);
  }
  finalize_kernel<<<1, 256, 0, stream>>>(part, dtwv, commit, out);
}

// Round 7
// 313.972 us; speedup vs baseline: 1.2228x; 1.1243x over previous
//
#include <hip/hip_runtime.h>
#include <math.h>

// VQVAE loss: total = huber_mean(x_hat - x) + 0.1 * mean_b(softDTW(x, x_hat)) + commit
// B=64, L=512, C=16, gamma=0.1, INF=1e10.
//
// Round 7 = identical resubmit (rounds 4-6 hit GPU-acquisition timeouts, never ran).
//   NaN fix vs round 3: exp2 args MUST be (mv - md) * kC1 (subtract first, <= 0 by
//   construction), NOT fmaf(md, -kC1, mv*kC1): the fma's exact product minus the
//   rounded mv*kC1 can be +8192 at mv=1e10 (ulp 16384) -> exp2f(+8192)=inf -> NaN.
//
// DTW: intra-block wave pipeline, no per-step barrier.
//  - neighbor (i-1) via DPP row_shr:1 + row_bcast15 (VALU-latency cross-lane),
//    lane0 boundary from a register-prefetched LDS ring (8-step double buffer).
//  - flag publish with bare lgkmcnt(0) (no vmcnt drain of the P prefetch queue).
//  - GEMM stores full d(i,j) = ||x_i||^2 + ||y_j||^2 - 2 x_i.y_j diagonal-packed.

#define INFV 1.0e10f
static constexpr float kC1 = 14.4269504088896f;    // log2(e)/gamma  (gamma=0.1)
static constexpr float kC2 = 0.0693147180559945f;  // gamma*ln(2)

// cells before anti-diagonal k (per batch), L=512; total = 262144
__device__ __forceinline__ int diag_off(int k) {
  if (k <= 512) return (k * (k + 1)) >> 1;
  int u = k - 512;
  return 131328 + 511 * u - ((u * (u - 1)) >> 1);
}
__device__ __forceinline__ int diag_i0(int k) { return k < 512 ? 0 : k - 511; }
// fdiag(k) = diag_off(k) - diag_i0(k): lane address = Dp + fdiag(k) + i
__device__ __forceinline__ int fdiag(int k) {
  if (k <= 511) return (k * (k + 1)) >> 1;
  int u = k - 512;
  return 131327 + 510 * u - ((u * (u - 1)) >> 1);
}

// ---------------- Huber ----------------
__device__ __forceinline__ float huber1(float d) {
  float ad = fabsf(d);
  return ad <= 1.0f ? 0.5f * d * d : ad - 0.5f;
}

__global__ __launch_bounds__(256) void huber_kernel(const float* __restrict__ x,
                                                    const float* __restrict__ xh,
                                                    float* __restrict__ part) {
  int t = threadIdx.x;
  int gid = blockIdx.x * 256 + t;
  float s = 0.f;
  for (int i = gid; i < 131072; i += 65536) {
    float4 a = ((const float4*)x)[i];
    float4 b = ((const float4*)xh)[i];
    s += huber1(b.x - a.x) + huber1(b.y - a.y) + huber1(b.z - a.z) + huber1(b.w - a.w);
  }
  for (int o = 32; o > 0; o >>= 1) s += __shfl_down(s, o, 64);
  __shared__ float ws4[4];
  if ((t & 63) == 0) ws4[t >> 6] = s;
  __syncthreads();
  if (t == 0) part[blockIdx.x] = ws4[0] + ws4[1] + ws4[2] + ws4[3];
}

// ---------------- GEMM -> packed-diagonal full distance d ----------------
__global__ __launch_bounds__(256) void gemm_diag_kernel(const float* __restrict__ x,
                                                        const float* __restrict__ xh,
                                                        float* __restrict__ Dp) {
  const int b = blockIdx.z;
  const int ti = blockIdx.x;
  const int tj = blockIdx.y;
  const int t = threadIdx.x;
  __shared__ float sm[64 * 67];
  float* xsT = sm;
  float* ysT = sm + 16 * 68;
  const float* xb = x + ((size_t)b * 8192) + ti * 1024;
  const float* yb = xh + ((size_t)b * 8192) + tj * 1024;
  {
    float4 xv = ((const float4*)xb)[t];
    float4 yv = ((const float4*)yb)[t];
    int r = t >> 2, c0 = (t & 3) << 2;
    xsT[(c0 + 0) * 68 + r] = xv.x;
    xsT[(c0 + 1) * 68 + r] = xv.y;
    xsT[(c0 + 2) * 68 + r] = xv.z;
    xsT[(c0 + 3) * 68 + r] = xv.w;
    ysT[(c0 + 0) * 68 + r] = yv.x;
    ysT[(c0 + 1) * 68 + r] = yv.y;
    ysT[(c0 + 2) * 68 + r] = yv.z;
    ysT[(c0 + 3) * 68 + r] = yv.w;
  }
  __syncthreads();
  const int tm = t & 15, tn = t >> 4;
  float acc[4][4] = {};
  float y2a[4] = {};
  float x2a[4] = {};
#pragma unroll
  for (int c = 0; c < 16; ++c) {
    float4 xv = *(const float4*)&xsT[c * 68 + tm * 4];
    float4 yv = *(const float4*)&ysT[c * 68 + tn * 4];
    float xr[4] = {xv.x, xv.y, xv.z, xv.w};
    float yr[4] = {yv.x, yv.y, yv.z, yv.w};
#pragma unroll
    for (int n = 0; n < 4; ++n) {
      y2a[n] = fmaf(yr[n], yr[n], y2a[n]);
#pragma unroll
      for (int m = 0; m < 4; ++m) acc[m][n] = fmaf(xr[m], yr[n], acc[m][n]);
    }
#pragma unroll
    for (int m = 0; m < 4; ++m) x2a[m] = fmaf(xr[m], xr[m], x2a[m]);
  }
  __syncthreads();
#pragma unroll
  for (int m = 0; m < 4; ++m)
#pragma unroll
    for (int n = 0; n < 4; ++n)
      sm[(tm * 4 + m) * 67 + (tn * 4 + n)] = fmaf(-2.0f, acc[m][n], x2a[m] + y2a[n]);
  __syncthreads();
  const int lane = t & 63, wv = t >> 6;
  float* outb = Dp + (size_t)b * 262144;
  const int kbase = ti * 64 + tj * 64;
  for (int s = wv; s < 127; s += 4) {
    int ilo = s > 63 ? s - 63 : 0;
    int ihi = s < 63 ? s : 63;
    if (lane >= ilo && lane <= ihi) {
      float v = sm[lane * 67 + (s - lane)];
      int k = kbase + s;
      outb[diag_off(k) - diag_i0(k) + (ti * 64 + lane)] = v;
    }
  }
}

// ---------------- DTW: wave-pipelined, DPP neighbor, reg-prefetched ring ----------------
// PC: current-step d value; RC: current-step ring value (lane0 boundary)
// PN/RN: prefetch destinations for step kk+8.
// NB: exp2 args are (mv - v) * kC1 with the SUBTRACT FIRST — guaranteed <= 0, no overflow.
#define PSTEP(PC, RC, PN, RN)                                                          \
  do {                                                                                 \
    {                                                                                  \
      int kc = kk + 8; kc = kc > 575 ? 575 : kc;                                       \
      int kg = k0 + kc;                                                                \
      PN = DbL[fdiag(kg)];                                                             \
      int ri = kc + 63; ri = ri > 574 ? 574 : ri;                                      \
      RN = ringPrev[ri];                                                               \
    }                                                                                  \
    int vi = __float_as_int(vprev);                                                    \
    float bs = __int_as_float(__builtin_amdgcn_update_dpp(0, vi, 0x111, 0xF, 0xF, true)); \
    float bb = __int_as_float(__builtin_amdgcn_update_dpp(0, vi, 0x142, 0xF, 0xF, true)); \
    float bval = fixl ? bb : bs;                                                       \
    float l0v = w ? RC : INFV;                                                         \
    bval = isl0 ? l0v : bval;                                                          \
    float mv = fminf(fminf(aval, bval), vprev);                                        \
    float md = __builtin_amdgcn_fmed3f(aval, bval, vprev);                             \
    float mx = fmaxf(fmaxf(aval, bval), vprev);                                        \
    float e1 = exp2f((mv - md) * kC1);                                                 \
    float e2 = exp2f((mv - mx) * kC1);                                                 \
    float lg = log2f(1.0f + e1 + e2);                                                  \
    float d_eff = ((unsigned)(kk - lane) <= 511u) ? PC : INFV;                         \
    float val = fmaf(-kC2, lg, mv + d_eff);                                            \
    if (lane == 63) ringOwn[kk] = val;                                                 \
    aval = bval;                                                                       \
    vprev = val;                                                                       \
    ++kk;                                                                              \
  } while (0)

__global__ __launch_bounds__(512) void dtw_pipe2_kernel(const float* __restrict__ Dp,
                                                        float* __restrict__ outv) {
  const int b = blockIdx.x;
  const int tid = threadIdx.x;
  const int w = tid >> 6;
  const int lane = tid & 63;
  __shared__ float ring[8][576];
  __shared__ int flags[8];
  if (tid < 8) flags[tid] = 0;
  __syncthreads();
  volatile int* vflags = flags;

  const bool isl0 = (lane == 0);
  const bool fixl = ((lane & 15) == 0) && (lane != 0);
  const float* DbL = Dp + (size_t)b * 262144 + tid;  // per-lane base (row i = tid)
  const int k0 = w << 6;
  float* ringOwn = ring[w];
  const float* ringPrev = ring[(w + 7) & 7];

  if (w) {
    while (vflags[w - 1] < 71) {}
  }
  asm volatile("" ::: "memory");

  float pA[8], pB[8], rA[8], rB[8];
#pragma unroll
  for (int j = 0; j < 8; ++j) {
    pA[j] = DbL[fdiag(k0 + j)];
    rA[j] = ringPrev[63 + j];
  }
  float aval = (tid == 0) ? 0.0f : INFV;  // virtual corner R(-1,-1)=0 for cell (0,0)
  float vprev = INFV;
  int kk = 0;

#pragma unroll 1
  for (int it = 0; it < 36; ++it) {
    if (w) {
      int need = kk + 87;
      need = need > 575 ? 575 : need;
      while (vflags[w - 1] < need) {}
    }
    asm volatile("" ::: "memory");
    PSTEP(pA[0], rA[0], pB[0], rB[0]);
    PSTEP(pA[1], rA[1], pB[1], rB[1]);
    PSTEP(pA[2], rA[2], pB[2], rB[2]);
    PSTEP(pA[3], rA[3], pB[3], rB[3]);
    PSTEP(pA[4], rA[4], pB[4], rB[4]);
    PSTEP(pA[5], rA[5], pB[5], rB[5]);
    PSTEP(pA[6], rA[6], pB[6], rB[6]);
    PSTEP(pA[7], rA[7], pB[7], rB[7]);
    PSTEP(pB[0], rB[0], pA[0], rA[0]);
    PSTEP(pB[1], rB[1], pA[1], rA[1]);
    PSTEP(pB[2], rB[2], pA[2], rA[2]);
    PSTEP(pB[3], rB[3], pA[3], rA[3]);
    PSTEP(pB[4], rB[4], pA[4], rA[4]);
    PSTEP(pB[5], rB[5], pA[5], rA[5]);
    PSTEP(pB[6], rB[6], pA[6], rA[6]);
    PSTEP(pB[7], rB[7], pA[7], rA[7]);
    asm volatile("s_waitcnt lgkmcnt(0)" ::: "memory");  // ring stores visible (LDS only)
    if (lane == 63) vflags[w] = kk;
  }
  // cell (511,511) was written to ring[7][574] by wave 7 lane 63 at kk=574
  if (tid == 511) outv[b] = ringOwn[574];
}

// ---------------- DTW fallback (fused dot, no workspace matrix) ----------------
__device__ __forceinline__ float dot16(const float4& a, const float4& b2,
                                       const float4& c, const float4& d,
                                       const float4* yp) {
  float4 q0 = yp[0], q1 = yp[1], q2 = yp[2], q3 = yp[3];
  float s = a.x * q0.x;
  s = fmaf(a.y, q0.y, s); s = fmaf(a.z, q0.z, s); s = fmaf(a.w, q0.w, s);
  s = fmaf(b2.x, q1.x, s); s = fmaf(b2.y, q1.y, s); s = fmaf(b2.z, q1.z, s); s = fmaf(b2.w, q1.w, s);
  s = fmaf(c.x, q2.x, s); s = fmaf(c.y, q2.y, s); s = fmaf(c.z, q2.z, s); s = fmaf(c.w, q2.w, s);
  s = fmaf(d.x, q3.x, s); s = fmaf(d.y, q3.y, s); s = fmaf(d.z, q3.z, s); s = fmaf(d.w, q3.w, s);
  return s;
}

#define DTW_FSTEP(W, R1, R2)                                                \
  do {                                                                      \
    int j = k - tid;                                                        \
    bool valid = (j >= 0) && (j < 512);                                     \
    int jc = valid ? j : 0;                                                 \
    float av = R2[tid];                                                     \
    float bv = R1[tid];                                                     \
    float dotv = dot16(xa, xb4, xc4, xd4, (const float4*)&ysl[jc * 20]);    \
    float mv = fminf(fminf(av, bv), vprev);                                 \
    float ssum = exp2f((mv - av) * kC1) + exp2f((mv - bv) * kC1) +          \
                 exp2f((mv - vprev) * kC1);                                 \
    float sm3 = fmaf(-kC2, log2f(ssum), mv);                                \
    float dd = fmaf(-2.0f, dotv, x2 + y2s[jc]);                             \
    float val = valid ? (dd + sm3) : INFV;                                  \
    W[tid + 1] = val;                                                      \
    vprev = val;                                                            \
    __syncthreads();                                                        \
    ++k;                                                                    \
  } while (0)

__global__ __launch_bounds__(512) void dtw_fused_kernel(const float* __restrict__ x,
                                                        const float* __restrict__ xh,
                                                        float* __restrict__ outv) {
  const int b = blockIdx.x;
  const int tid = threadIdx.x;
  __shared__ float ysl[512 * 20];
  __shared__ float y2s[512];
  __shared__ float rA[516], rB[516], rC[516];
  const float* xr = x + (size_t)b * 8192 + tid * 16;
  const float* yr = xh + (size_t)b * 8192 + tid * 16;
  float4 xa = *(const float4*)(xr + 0);
  float4 xb4 = *(const float4*)(xr + 4);
  float4 xc4 = *(const float4*)(xr + 8);
  float4 xd4 = *(const float4*)(xr + 12);
  float x2 = xa.x * xa.x + xa.y * xa.y + xa.z * xa.z + xa.w * xa.w +
             xb4.x * xb4.x + xb4.y * xb4.y + xb4.z * xb4.z + xb4.w * xb4.w +
             xc4.x * xc4.x + xc4.y * xc4.y + xc4.z * xc4.z + xc4.w * xc4.w +
             xd4.x * xd4.x + xd4.y * xd4.y + xd4.z * xd4.z + xd4.w * xd4.w;
  {
    float4 q0 = *(const float4*)(yr + 0);
    float4 q1 = *(const float4*)(yr + 4);
    float4 q2 = *(const float4*)(yr + 8);
    float4 q3 = *(const float4*)(yr + 12);
    *(float4*)&ysl[tid * 20 + 0] = q0;
    *(float4*)&ysl[tid * 20 + 4] = q1;
    *(float4*)&ysl[tid * 20 + 8] = q2;
    *(float4*)&ysl[tid * 20 + 12] = q3;
    y2s[tid] = q0.x * q0.x + q0.y * q0.y + q0.z * q0.z + q0.w * q0.w +
               q1.x * q1.x + q1.y * q1.y + q1.z * q1.z + q1.w * q1.w +
               q2.x * q2.x + q2.y * q2.y + q2.z * q2.z + q2.w * q2.w +
               q3.x * q3.x + q3.y * q3.y + q3.z * q3.z + q3.w * q3.w;
  }
  rA[tid] = INFV;
  rB[tid] = INFV;
  rC[tid] = INFV;
  if (tid == 0) { rA[512] = INFV; rB[512] = INFV; rC[512] = INFV; }
  __syncthreads();
  float dot00 = dot16(xa, xb4, xc4, xd4, (const float4*)&ysl[0]);
  float d00 = fmaf(-2.0f, dot00, x2 + y2s[0]);
  float vprev = (tid == 0) ? d00 : INFV;
  if (tid == 0) rC[1] = d00;
  int k = 1;
  __syncthreads();
#pragma unroll 1
  for (int it = 0; it < 340; ++it) {
    DTW_FSTEP(rA, rC, rB);
    DTW_FSTEP(rB, rA, rC);
    DTW_FSTEP(rC, rB, rA);
  }
  DTW_FSTEP(rA, rC, rB);
  DTW_FSTEP(rB, rA, rC);
  if (tid == 511) outv[b] = vprev;
}

// ---------------- finalize ----------------
__global__ __launch_bounds__(256) void finalize_kernel(const float* __restrict__ part,
                                                       const float* __restrict__ dtwv,
                                                       const float* __restrict__ commit,
                                                       float* __restrict__ out) {
  int t = threadIdx.x;
  float h = part[t];
  float dv = (t < 64) ? dtwv[t] : 0.f;
  for (int o = 32; o > 0; o >>= 1) {
    h += __shfl_down(h, o, 64);
    dv += __shfl_down(dv, o, 64);
  }
  __shared__ float sh[4], sd[4];
  if ((t & 63) == 0) { sh[t >> 6] = h; sd[t >> 6] = dv; }
  __syncthreads();
  if (t == 0) {
    float hs = sh[0] + sh[1] + sh[2] + sh[3];
    float ds = sd[0] + sd[1] + sd[2] + sd[3];
    float hm = hs * (1.0f / 524288.0f);
    float smv = ds * (0.1f / 64.0f);
    float cm = commit[0];
    out[0] = hm + smv + cm;
    out[1] = hm;
    out[2] = smv;
    out[3] = cm;
  }
}

extern "C" void kernel_launch(void* const* d_in, const int* in_sizes, int n_in,
                              void* d_out, int out_size, void* d_ws, size_t ws_size,
                              hipStream_t stream) {
  (void)in_sizes; (void)n_in; (void)out_size;
  const float* x = (const float*)d_in[0];
  const float* xh = (const float*)d_in[1];
  const float* commit = (const float*)d_in[2];
  float* out = (float*)d_out;
  float* ws = (float*)d_ws;
  float* part = ws;        // 256 floats
  float* dtwv = ws + 256;  // 64 floats
  float* Dp = ws + 512;    // 64 * 262144 floats
  const size_t need = 2048 + (size_t)64 * 262144 * 4;

  huber_kernel<<<256, 256, 0, stream>>>(x, xh, part);
  if (ws_size >= need) {
    gemm_diag_kernel<<<dim3(8, 8, 64), 256, 0, stream>>>(x, xh, Dp);
    dtw_pipe2_kernel<<<64, 512, 0, stream>>>(Dp, dtwv);
  } else {
    dtw_fused_kernel<<<64, 512, 0, stream>>>(x, xh, dtwv);
  }
  finalize_kernel<<<1, 256, 0, stream>>>(part, dtwv, commit, out);
}